// Round 1
// baseline (194.698 us; speedup 1.0000x reference)
//
#include <hip/hip_runtime.h>
#include <stdint.h>

#define HIST_BITS  13
#define HIST_BINS  (1 << HIST_BITS)    // 8192
#define HIST_SHIFT (32 - HIST_BITS)    // 19
#define CAP        8192
#define SORT_N     8192

// ws layout (bytes):
//   [0]      double   sum_sq
//   [8]      unsigned cand_count
//   [12]     unsigned cutoff_bucket
//   [16]     unsigned hist[HIST_BINS]                (32 KB)
//   [32784]  uint64_t cand[CAP]                      (64 KB)
//   [98320]  unsigned keys[B]   (optional, if ws_size permits; 16 MB)
#define OFF_SUM    0
#define OFF_COUNT  8
#define OFF_CUTOFF 12
#define OFF_HIST   16
#define OFF_CAND   (OFF_HIST + HIST_BINS * 4)
#define OFF_KEYS   (OFF_CAND + CAP * 8)

__device__ __forceinline__ unsigned row_key(const float4& a, const float4& b) {
    // Bit-exact match of numpy: sequential f32 sum of squares, no FMA, then *0.25f
    float d0 = __fadd_rn(a.x, -b.x);
    float d1 = __fadd_rn(a.y, -b.y);
    float d2 = __fadd_rn(a.z, -b.z);
    float d3 = __fadd_rn(a.w, -b.w);
    float s0 = __fmul_rn(d0, d0);
    float s1 = __fmul_rn(d1, d1);
    float s2 = __fmul_rn(d2, d2);
    float s3 = __fmul_rn(d3, d3);
    float sum = __fadd_rn(__fadd_rn(__fadd_rn(s0, s1), s2), s3);
    float m = __fmul_rn(sum, 0.25f);
    return __float_as_uint(m);   // m >= 0 -> uint order == float order
}

__global__ void mse_pass_a(const float4* __restrict__ inp, const float4* __restrict__ tgt,
                           int B, double* __restrict__ sum_sq, unsigned* __restrict__ hist,
                           unsigned* __restrict__ keys, int store_keys) {
    __shared__ unsigned lhist[HIST_BINS];
    for (int i = threadIdx.x; i < HIST_BINS; i += blockDim.x) lhist[i] = 0;
    __syncthreads();

    double acc = 0.0;
    int stride = gridDim.x * blockDim.x;
    for (int i = blockIdx.x * blockDim.x + threadIdx.x; i < B; i += stride) {
        float4 a = inp[i];
        float4 b = tgt[i];
        float d0 = __fadd_rn(a.x, -b.x);
        float d1 = __fadd_rn(a.y, -b.y);
        float d2 = __fadd_rn(a.z, -b.z);
        float d3 = __fadd_rn(a.w, -b.w);
        float s0 = __fmul_rn(d0, d0);
        float s1 = __fmul_rn(d1, d1);
        float s2 = __fmul_rn(d2, d2);
        float s3 = __fmul_rn(d3, d3);
        float sum = __fadd_rn(__fadd_rn(__fadd_rn(s0, s1), s2), s3);
        float m = __fmul_rn(sum, 0.25f);
        unsigned key = __float_as_uint(m);
        atomicAdd(&lhist[key >> HIST_SHIFT], 1u);
        if (store_keys) keys[i] = key;
        acc += (double)s0 + (double)s1 + (double)s2 + (double)s3;
    }

    // wave reduce (64 lanes) then block reduce the double accumulator
    for (int off = 32; off > 0; off >>= 1) acc += __shfl_down(acc, off, 64);
    __shared__ double wacc[8];
    int wid = threadIdx.x >> 6, lane = threadIdx.x & 63;
    int nw = blockDim.x >> 6;
    if (lane == 0) wacc[wid] = acc;
    __syncthreads();
    if (threadIdx.x == 0) {
        double t = 0.0;
        for (int w = 0; w < nw; ++w) t += wacc[w];
        atomicAdd(sum_sq, t);
    }

    // merge LDS histogram into global (only nonzero bins)
    __syncthreads();
    for (int i = threadIdx.x; i < HIST_BINS; i += blockDim.x) {
        unsigned v = lhist[i];
        if (v) atomicAdd(&hist[i], v);
    }
}

__global__ void mse_scan(const unsigned* __restrict__ hist, unsigned* __restrict__ cutoff, int n) {
    __shared__ unsigned psum[256];
    __shared__ unsigned excl[256];
    int tid = threadIdx.x;
    const int per = HIST_BINS / 256;  // 32 bins per thread
    unsigned s = 0;
    int base_bin = tid * per;
    for (int i = 0; i < per; ++i) s += hist[base_bin + i];
    psum[tid] = s;
    __syncthreads();
    if (tid == 0) {
        unsigned run = 0;
        for (int i = 0; i < 256; ++i) { excl[i] = run; run += psum[i]; }
    }
    __syncthreads();
    unsigned base = excl[tid];
    unsigned un = (unsigned)n;
    if (base < un && base + psum[tid] >= un) {
        unsigned run = base;
        for (int i = 0; i < per; ++i) {
            run += hist[base_bin + i];
            if (run >= un) { *cutoff = (unsigned)(base_bin + i); break; }
        }
    }
}

__global__ void mse_pass_b(const float4* __restrict__ inp, const float4* __restrict__ tgt,
                           const unsigned* __restrict__ keys, int use_keys, int B,
                           const unsigned* __restrict__ cutoff, unsigned* __restrict__ count,
                           unsigned long long* __restrict__ cand) {
    unsigned cut = *cutoff;
    int stride = gridDim.x * blockDim.x;
    for (int i = blockIdx.x * blockDim.x + threadIdx.x; i < B; i += stride) {
        unsigned key;
        if (use_keys) {
            key = keys[i];
        } else {
            key = row_key(inp[i], tgt[i]);
        }
        if ((key >> HIST_SHIFT) <= cut) {
            unsigned pos = atomicAdd(count, 1u);
            if (pos < CAP) cand[pos] = ((unsigned long long)key << 32) | (unsigned)i;
        }
    }
}

__global__ __launch_bounds__(1024) void mse_final(const double* __restrict__ sum_sq,
                                                  const unsigned* __restrict__ count,
                                                  const unsigned long long* __restrict__ cand,
                                                  float* __restrict__ out, int n,
                                                  long long total_elems) {
    __shared__ unsigned long long lds[SORT_N];
    unsigned cnt = *count;
    if (cnt > CAP) cnt = CAP;
    for (int i = threadIdx.x; i < SORT_N; i += 1024)
        lds[i] = (i < (int)cnt) ? cand[i] : 0xFFFFFFFFFFFFFFFFULL;
    __syncthreads();

    // bitonic sort ascending on (valbits, idx)
    for (int k = 2; k <= SORT_N; k <<= 1) {
        for (int j = k >> 1; j > 0; j >>= 1) {
            for (int t = threadIdx.x; t < SORT_N; t += 1024) {
                int ixj = t ^ j;
                if (ixj > t) {
                    unsigned long long a = lds[t], b = lds[ixj];
                    bool up = ((t & k) == 0);
                    if ((a > b) == up) { lds[t] = b; lds[ixj] = a; }
                }
            }
            __syncthreads();
        }
    }

    if (threadIdx.x == 0) out[0] = (float)(*sum_sq / (double)total_elems);
    for (int i = threadIdx.x; i < n; i += 1024)
        out[1 + i] = (float)(unsigned)(lds[i] & 0xFFFFFFFFu);
}

extern "C" void kernel_launch(void* const* d_in, const int* in_sizes, int n_in,
                              void* d_out, int out_size, void* d_ws, size_t ws_size,
                              hipStream_t stream) {
    const float4* inp = (const float4*)d_in[0];
    const float4* tgt = (const float4*)d_in[1];
    int B = in_sizes[0] / 4;          // 4,000,000 rows
    int n = out_size - 1;             // 1024

    char* ws = (char*)d_ws;
    double*   sum_sq = (double*)(ws + OFF_SUM);
    unsigned* count  = (unsigned*)(ws + OFF_COUNT);
    unsigned* cutoff = (unsigned*)(ws + OFF_CUTOFF);
    unsigned* hist   = (unsigned*)(ws + OFF_HIST);
    unsigned long long* cand = (unsigned long long*)(ws + OFF_CAND);
    unsigned* keys   = (unsigned*)(ws + OFF_KEYS);

    size_t need_keys = (size_t)OFF_KEYS + (size_t)B * 4;
    int store_keys = (ws_size >= need_keys) ? 1 : 0;

    // zero header + histogram (ws is poisoned, and replays must start clean)
    hipMemsetAsync(d_ws, 0, OFF_CAND, stream);

    int threads = 256;
    int blocks = (B + threads - 1) / threads;
    if (blocks > 2048) blocks = 2048;

    mse_pass_a<<<blocks, threads, 0, stream>>>(inp, tgt, B, sum_sq, hist, keys, store_keys);
    mse_scan<<<1, 256, 0, stream>>>(hist, cutoff, n);
    mse_pass_b<<<blocks, threads, 0, stream>>>(inp, tgt, keys, store_keys, B, cutoff, count, cand);
    mse_final<<<1, 1024, 0, stream>>>(sum_sq, count, cand, (float*)d_out, n, (long long)B * 4);
}

// Round 2
// 114.447 us; speedup vs baseline: 1.7012x; 1.7012x over previous
//
#include <hip/hip_runtime.h>
#include <stdint.h>

#define HIST_BITS  13
#define HIST_BINS  (1 << HIST_BITS)    // 8192
#define HIST_SHIFT (32 - HIST_BITS)    // 19
#define CAP        8192

// ws layout (bytes):
//   [0]      double   sum_sq
//   [8]      unsigned cand_count
//   [12]     unsigned cutoff_bucket
//   [16]     unsigned hist[HIST_BINS]                (32 KB)
//   [32784]  uint64_t cand[CAP]                      (64 KB)
//   [98320]  unsigned keys[B]   (optional, if ws_size permits; 16 MB)
#define OFF_SUM    0
#define OFF_COUNT  8
#define OFF_CUTOFF 12
#define OFF_HIST   16
#define OFF_CAND   (OFF_HIST + HIST_BINS * 4)
#define OFF_KEYS   (OFF_CAND + CAP * 8)

__device__ __forceinline__ unsigned row_key(const float4& a, const float4& b) {
    // Bit-exact match of numpy: sequential f32 sum of squares, no FMA, then *0.25f
    float d0 = __fadd_rn(a.x, -b.x);
    float d1 = __fadd_rn(a.y, -b.y);
    float d2 = __fadd_rn(a.z, -b.z);
    float d3 = __fadd_rn(a.w, -b.w);
    float s0 = __fmul_rn(d0, d0);
    float s1 = __fmul_rn(d1, d1);
    float s2 = __fmul_rn(d2, d2);
    float s3 = __fmul_rn(d3, d3);
    float sum = __fadd_rn(__fadd_rn(__fadd_rn(s0, s1), s2), s3);
    float m = __fmul_rn(sum, 0.25f);
    return __float_as_uint(m);   // m >= 0 -> uint order == float order
}

__global__ void mse_pass_a(const float4* __restrict__ inp, const float4* __restrict__ tgt,
                           int B, double* __restrict__ sum_sq, unsigned* __restrict__ hist,
                           unsigned* __restrict__ keys, int store_keys) {
    __shared__ unsigned lhist[HIST_BINS];
    for (int i = threadIdx.x; i < HIST_BINS; i += blockDim.x) lhist[i] = 0;
    __syncthreads();

    double acc = 0.0;
    int stride = gridDim.x * blockDim.x;
    for (int i = blockIdx.x * blockDim.x + threadIdx.x; i < B; i += stride) {
        float4 a = inp[i];
        float4 b = tgt[i];
        float d0 = __fadd_rn(a.x, -b.x);
        float d1 = __fadd_rn(a.y, -b.y);
        float d2 = __fadd_rn(a.z, -b.z);
        float d3 = __fadd_rn(a.w, -b.w);
        float s0 = __fmul_rn(d0, d0);
        float s1 = __fmul_rn(d1, d1);
        float s2 = __fmul_rn(d2, d2);
        float s3 = __fmul_rn(d3, d3);
        float sum = __fadd_rn(__fadd_rn(__fadd_rn(s0, s1), s2), s3);
        float m = __fmul_rn(sum, 0.25f);
        unsigned key = __float_as_uint(m);
        atomicAdd(&lhist[key >> HIST_SHIFT], 1u);
        if (store_keys) keys[i] = key;
        acc += (double)s0 + (double)s1 + (double)s2 + (double)s3;
    }

    // wave reduce (64 lanes) then block reduce the double accumulator
    for (int off = 32; off > 0; off >>= 1) acc += __shfl_down(acc, off, 64);
    __shared__ double wacc[8];
    int wid = threadIdx.x >> 6, lane = threadIdx.x & 63;
    int nw = blockDim.x >> 6;
    if (lane == 0) wacc[wid] = acc;
    __syncthreads();
    if (threadIdx.x == 0) {
        double t = 0.0;
        for (int w = 0; w < nw; ++w) t += wacc[w];
        atomicAdd(sum_sq, t);
    }

    // merge LDS histogram into global (only nonzero bins)
    __syncthreads();
    for (int i = threadIdx.x; i < HIST_BINS; i += blockDim.x) {
        unsigned v = lhist[i];
        if (v) atomicAdd(&hist[i], v);
    }
}

__global__ void mse_scan(const unsigned* __restrict__ hist, unsigned* __restrict__ cutoff, int n) {
    __shared__ unsigned psum[256];
    __shared__ unsigned excl[256];
    int tid = threadIdx.x;
    const int per = HIST_BINS / 256;  // 32 bins per thread
    unsigned s = 0;
    int base_bin = tid * per;
    for (int i = 0; i < per; ++i) s += hist[base_bin + i];
    psum[tid] = s;
    __syncthreads();
    if (tid == 0) {
        unsigned run = 0;
        for (int i = 0; i < 256; ++i) { excl[i] = run; run += psum[i]; }
    }
    __syncthreads();
    unsigned base = excl[tid];
    unsigned un = (unsigned)n;
    if (base < un && base + psum[tid] >= un) {
        unsigned run = base;
        for (int i = 0; i < per; ++i) {
            run += hist[base_bin + i];
            if (run >= un) { *cutoff = (unsigned)(base_bin + i); break; }
        }
    }
}

__global__ void mse_pass_b(const float4* __restrict__ inp, const float4* __restrict__ tgt,
                           const unsigned* __restrict__ keys, int use_keys, int B,
                           const unsigned* __restrict__ cutoff, unsigned* __restrict__ count,
                           unsigned long long* __restrict__ cand) {
    unsigned cut = *cutoff;
    int stride = gridDim.x * blockDim.x;
    for (int i = blockIdx.x * blockDim.x + threadIdx.x; i < B; i += stride) {
        unsigned key;
        if (use_keys) {
            key = keys[i];
        } else {
            key = row_key(inp[i], tgt[i]);
        }
        if ((key >> HIST_SHIFT) <= cut) {
            unsigned pos = atomicAdd(count, 1u);
            if (pos < CAP) cand[pos] = ((unsigned long long)key << 32) | (unsigned)i;
        }
    }
}

// Rank-by-counting: keys (valbits<<32 | idx) are unique, so ranks 0..cnt-1 are
// a permutation. Each thread owning candidate i counts how many keys are
// smaller and scatters the index straight to out[1+rank]. Inner loop is a
// same-address LDS broadcast read per iteration (conflict-free).
__global__ __launch_bounds__(256) void mse_final(const double* __restrict__ sum_sq,
                                                 const unsigned* __restrict__ count,
                                                 const unsigned long long* __restrict__ cand,
                                                 float* __restrict__ out, int n,
                                                 long long total_elems) {
    __shared__ unsigned long long lds[CAP];
    unsigned cnt = *count;
    if (cnt > CAP) cnt = CAP;

    for (int i = threadIdx.x; i < (int)cnt; i += blockDim.x)
        lds[i] = cand[i];
    __syncthreads();

    if (blockIdx.x == 0 && threadIdx.x == 0)
        out[0] = (float)(*sum_sq / (double)total_elems);

    int g = blockIdx.x * blockDim.x + threadIdx.x;
    int gs = gridDim.x * blockDim.x;
    for (int i = g; i < (int)cnt; i += gs) {
        unsigned long long mine = lds[i];
        int rank = 0;
        for (int j = 0; j < (int)cnt; ++j)
            rank += (lds[j] < mine) ? 1 : 0;
        if (rank < n)
            out[1 + rank] = (float)(unsigned)(mine & 0xFFFFFFFFu);
    }
}

extern "C" void kernel_launch(void* const* d_in, const int* in_sizes, int n_in,
                              void* d_out, int out_size, void* d_ws, size_t ws_size,
                              hipStream_t stream) {
    const float4* inp = (const float4*)d_in[0];
    const float4* tgt = (const float4*)d_in[1];
    int B = in_sizes[0] / 4;          // 4,000,000 rows
    int n = out_size - 1;             // 1024

    char* ws = (char*)d_ws;
    double*   sum_sq = (double*)(ws + OFF_SUM);
    unsigned* count  = (unsigned*)(ws + OFF_COUNT);
    unsigned* cutoff = (unsigned*)(ws + OFF_CUTOFF);
    unsigned* hist   = (unsigned*)(ws + OFF_HIST);
    unsigned long long* cand = (unsigned long long*)(ws + OFF_CAND);
    unsigned* keys   = (unsigned*)(ws + OFF_KEYS);

    size_t need_keys = (size_t)OFF_KEYS + (size_t)B * 4;
    int store_keys = (ws_size >= need_keys) ? 1 : 0;

    // zero header + histogram (ws is poisoned, and replays must start clean)
    hipMemsetAsync(d_ws, 0, OFF_CAND, stream);

    int threads = 256;
    int blocks = (B + threads - 1) / threads;
    if (blocks > 2048) blocks = 2048;

    mse_pass_a<<<blocks, threads, 0, stream>>>(inp, tgt, B, sum_sq, hist, keys, store_keys);
    mse_scan<<<1, 256, 0, stream>>>(hist, cutoff, n);
    mse_pass_b<<<blocks, threads, 0, stream>>>(inp, tgt, keys, store_keys, B, cutoff, count, cand);
    mse_final<<<16, 256, 0, stream>>>(sum_sq, count, cand, (float*)d_out, n, (long long)B * 4);
}